// Round 9
// baseline (175.380 us; speedup 1.0000x reference)
//
#include <hip/hip_runtime.h>
#include <hip/hip_bf16.h>
#include <stdint.h>

// Problem constants (SpatialDecoder: B=128, N=1024, DM=64, S=2, D_IN=68)
#define NB 128
#define NN 1024
#define NDM 64

typedef __bf16 bf16;
typedef __bf16 bf16x8_t __attribute__((ext_vector_type(8)));
typedef __bf16 bf16x4_t __attribute__((ext_vector_type(4)));
typedef float f32x4 __attribute__((ext_vector_type(4)));

// ---------------------------------------------------------------------------
// k_prep: weight prep only (adj cast lives in k_build). Grid 71 x 256.
// ---------------------------------------------------------------------------
__global__ __launch_bounds__(256) void k_prep(
    const float* __restrict__ W_in, const float* __restrict__ b_in,
    const float* __restrict__ W_gc, const float* __restrict__ b_gc,
    const float* __restrict__ W_out, const float* __restrict__ b_out,
    const float* __restrict__ W_read,
    bf16* __restrict__ WAT, float* __restrict__ WYX,
    float* __restrict__ BIAS, bf16* __restrict__ W1B, bf16* __restrict__ A2B,
    float* __restrict__ HBv) {
  int i = blockIdx.x * 256 + threadIdx.x;
  if (i < 8192) {  // WAT
    int r = i >> 6, cc = i & 63;
    int cq = cc >> 3, j = cc & 7;
    int c = ((cq ^ (r & 7)) << 3) + j;
    int s = r >> 6, o = r & 63;
    float val = 0.f;
    for (int k = 0; k < 64; ++k) val += W_gc[o * 128 + s * 64 + k] * W_in[k * 68 + 4 + c];
    WAT[i] = (bf16)val;
  } else if (i < 8704) {  // WYX
    int idx = i - 8192;
    int r = idx >> 2, jj = idx & 3;
    int s = r >> 6, o = r & 63;
    float val = 0.f;
    for (int k = 0; k < 64; ++k) val += W_gc[o * 128 + s * 64 + k] * W_in[k * 68 + jj];
    WYX[idx] = val;
  } else if (i < 8832) {  // BIAS
    int r = i - 8704;
    int s = r >> 6, o = r & 63;
    float val = 0.f;
    for (int k = 0; k < 64; ++k) val += W_gc[o * 128 + s * 64 + k] * b_in[k];
    BIAS[r] = val;
  } else if (i < 12928) {  // W1B
    int j = i - 8832;
    int o = j >> 6, c = j & 63;
    W1B[j] = (bf16)W_out[o * 128 + c];
  } else if (i < 18048) {  // A2B (80x64)
    int j = i - 12928;
    int r = j >> 6, c = j & 63;
    float val = 0.f;
    if (r < 64) val = W_out[r * 128 + 64 + c];
    else if (r == 64) val = W_read[64 + c];
    A2B[j] = (bf16)val;
  } else if (i < 18112) {  // HBv
    int o = i - 18048;
    float val = b_out[o];
    for (int c = 0; c < 64; ++c) val += W_out[o * 128 + c] * b_gc[c];
    HBv[o] = val;
  }
}

// ---------------------------------------------------------------------------
// k_build (fused transpose + Y build). Grid (10, 128), 256 thr. (round-7)
// ---------------------------------------------------------------------------
__global__ __launch_bounds__(256) void k_build(
    const float* __restrict__ x, const float* __restrict__ m, const float* __restrict__ u,
    const float* __restrict__ h, const float* __restrict__ adj,
    const bf16* __restrict__ WAT,
    const float* __restrict__ WYX, const float* __restrict__ BIAS,
    bf16* __restrict__ adjb, bf16* __restrict__ Y, bf16* __restrict__ HT,
    float* __restrict__ out2) {
  __shared__ __align__(16) float T[64 * 128];     // 32 KB (reused as Y-tile)
  __shared__ __align__(16) bf16 HTs[128 * 64];    // 16 KB
  __shared__ __align__(16) bf16 WAs[128 * 64];    // 16 KB
  __shared__ __align__(16) float X4L[128 * 4];    // 2 KB
  __shared__ __align__(16) float WYXs[128 * 4];   // 2 KB
  __shared__ __align__(16) float biasL[128];
  const int t = threadIdx.x;

  if (blockIdx.x >= 8) {  // adj cast blocks: 256 blocks x 2048 float4
    const int chunk = (blockIdx.x - 8) * 128 + blockIdx.y;  // 0..255
#pragma unroll
    for (int k2 = 0; k2 < 8; ++k2) {
      int i = chunk * 2048 + k2 * 256 + t;
      float4 v = reinterpret_cast<const float4*>(adj)[i];
      bf16x4_t r;
      r.x = (bf16)v.x; r.y = (bf16)v.y; r.z = (bf16)v.z; r.w = (bf16)v.w;
      reinterpret_cast<bf16x4_t*>(adjb)[i] = r;
    }
    return;
  }

  const int vb = blockIdx.x * 128;
  const int b = blockIdx.y;

  for (int i = t; i < 2048; i += 256)
    __builtin_amdgcn_global_load_lds(
        (const uint32_t*)(h + (size_t)(b * 64 + (i >> 5)) * NN + vb + (i & 31) * 4),
        (uint32_t*)&T[i * 4], 16, 0, 0);
  for (int i = t; i < 1024; i += 256)
    __builtin_amdgcn_global_load_lds((const uint32_t*)(WAT + i * 8), (uint32_t*)&WAs[i * 8], 16, 0, 0);
  if (t < 128)
    __builtin_amdgcn_global_load_lds((const uint32_t*)(WYX + t * 4), (uint32_t*)&WYXs[t * 4], 16, 0, 0);
  if (t < 32)
    __builtin_amdgcn_global_load_lds((const uint32_t*)(BIAS + t * 4), (uint32_t*)&biasL[t * 4], 16, 0, 0);
  if (t < 128) {
    float4 x4;
    x4.x = x[(size_t)b * NN + vb + t];
    x4.y = m[(size_t)b * NN + vb + t];
    x4.z = u[(size_t)(b * 2) * NN + vb + t];
    x4.w = u[(size_t)(b * 2 + 1) * NN + vb + t];
    *reinterpret_cast<float4*>(&X4L[t * 4]) = x4;
  }
  __syncthreads();

  // transpose/pack: thread pair covers one v (HTs only)
  {
    const int v = t >> 1, half = t & 1;
#pragma unroll
    for (int cc = 0; cc < 4; ++cc) {
      int cq = half * 4 + cc;
      int cbase = (cq ^ (v & 7)) << 3;
      bf16x8_t pk;
#pragma unroll
      for (int j = 0; j < 8; ++j) pk[j] = (bf16)T[(cbase + j) * 128 + v];
      *reinterpret_cast<bf16x8_t*>(&HTs[v * 64 + cq * 8]) = pk;
    }
  }
  // h passthrough (exact f32) — last use of T as h-tile
  for (int i = t; i < 2048; i += 256) {
    int r = i >> 5, ck = i & 31;
    float4 hv = *reinterpret_cast<const float4*>(&T[r * 128 + ck * 4]);
    *reinterpret_cast<float4*>(&out2[(size_t)(b * 128 + 64 + r) * NN + vb + ck * 4]) = hv;
  }
  __syncthreads();

  // coalesced HT store: 16 KB contiguous per block
  {
    const bf16* HTs_b = HTs;
#pragma unroll
    for (int p = 0; p < 4; ++p) {
      int i = p * 256 + t;
      bf16x8_t v = *reinterpret_cast<const bf16x8_t*>(&HTs_b[i * 8]);
      *reinterpret_cast<bf16x8_t*>(&HT[((size_t)(b << 10) + vb) * 64 + i * 8]) = v;
    }
  }

  const int wave = t >> 6, lane = t & 63;
  const int q = lane >> 4, lx = lane & 7, o16 = lane & 15;
  const int offK0 = (q ^ lx) << 3, offK1 = ((q + 4) ^ lx) << 3;
  bf16* YT = reinterpret_cast<bf16*>(T);   // [128 rows][128 v] bf16 = 32 KB

#pragma unroll
  for (int vi = 0; vi < 2; ++vi) {
    const int vt = wave + vi * 4;
    const int vrow = vt * 16 + o16;
    bf16x8_t af0 = *reinterpret_cast<const bf16x8_t*>(&HTs[vrow * 64 + offK0]);
    bf16x8_t af1 = *reinterpret_cast<const bf16x8_t*>(&HTs[vrow * 64 + offK1]);
    float4 x4r[4];
#pragma unroll
    for (int r = 0; r < 4; ++r)
      x4r[r] = *reinterpret_cast<const float4*>(&X4L[(vt * 16 + q * 4 + r) * 4]);
    for (int nt = 0; nt < 8; ++nt) {
      const int rr = nt * 16 + o16;
      bf16x8_t bf0 = *reinterpret_cast<const bf16x8_t*>(&WAs[rr * 64 + offK0]);
      bf16x8_t bf1 = *reinterpret_cast<const bf16x8_t*>(&WAs[rr * 64 + offK1]);
      float bsv = biasL[rr];
      float4 wy = *reinterpret_cast<const float4*>(&WYXs[rr * 4]);
      f32x4 c0;
#pragma unroll
      for (int r = 0; r < 4; ++r)
        c0[r] = bsv + wy.x * x4r[r].x + wy.y * x4r[r].y + wy.z * x4r[r].z + wy.w * x4r[r].w;
      f32x4 acc = __builtin_amdgcn_mfma_f32_16x16x32_bf16(af0, bf0, c0, 0, 0, 0);
      acc = __builtin_amdgcn_mfma_f32_16x16x32_bf16(af1, bf1, acc, 0, 0, 0);
      bf16x4_t pk;
      pk.x = (bf16)acc[0]; pk.y = (bf16)acc[1]; pk.z = (bf16)acc[2]; pk.w = (bf16)acc[3];
      // LDS write, 8B chunk XOR-swizzled by row&7 (conflict-free)
      const int c8 = (vt * 4 + q) ^ ((rr & 7) << 2);
      *reinterpret_cast<bf16x4_t*>(&YT[rr * 128 + c8 * 4]) = pk;
    }
  }
  __syncthreads();

  // coalesced Y store: per instr 4 rows x 256B contiguous
#pragma unroll
  for (int p = 0; p < 8; ++p) {
    int i = p * 256 + t;
    int ro = i >> 4;                         // 0..127 = s*64+o
    int cc = (i & 15) * 2;                   // even logical 8B chunk
    int cs = cc ^ ((ro & 7) << 2);           // swizzled location
    bf16x8_t v = *reinterpret_cast<const bf16x8_t*>(&YT[ro * 128 + cs * 4]);
    int s = ro >> 6, o = ro & 63;
    *reinterpret_cast<bf16x8_t*>(&Y[(size_t)(b * 64 + o) * 2048 + s * 1024 + vb + (i & 15) * 8]) = v;
  }
}

// ---------------------------------------------------------------------------
// k_gemm: round-8 — 128x128 tile, 4 waves (2Mx2N, wave 64x64), 256 thr,
//   grid (64,8) = 512 blocks = 2 blocks/CU (64 KB LDS each).
//   Two independent barrier domains per CU break the read-burst/MFMA-burst
//   phase-lock (m114 mechanism: one block's MFMA covers the other's LDS
//   reads). Pipeline = round-5 structure verbatim: 2-deep ring, one
//   barrier/iter, cross-tile frag carry, counted lgkmcnt, setprio.
//   Epilogue = round-0 2-batch version. MFMA order per acc bit-identical.
// ---------------------------------------------------------------------------
__global__ __launch_bounds__(256, 2) void k_gemm(
    const bf16* __restrict__ Y, const bf16* __restrict__ ADJB,
    const bf16* __restrict__ HT,
    const bf16* __restrict__ W1B, const bf16* __restrict__ A2B,
    const float* __restrict__ HBv, const float* __restrict__ W_read,
    const float* __restrict__ b_read, const float* __restrict__ prelu_w,
    float* __restrict__ out0, float* __restrict__ out2) {
  __shared__ __align__(16) union SMem {
    struct { bf16 As[2][128 * 64]; bf16 Bs[2][128 * 64]; } st;  // 64 KB staging
    struct {
      bf16 gcs[2 * 128 * 72];   // 36.9 KB phase-2
      bf16 W1s[64 * 72];        // 9.2 KB
      bf16 A2s[80 * 72];        // 11.5 KB
      float HBs[64];
      float Wrs[64];
    } ep;
  } sm;

  const int t = threadIdx.x;
  const int wave = t >> 6, lane = t & 63;
  // XCD-affinity swizzle: 8 consecutive row-panels per XCD.
  const int lin = blockIdx.y * 64 + blockIdx.x;
  const int xcd = lin & 7, rest = lin >> 3;          // rest 0..63
  const int rowA = (xcd * 8 + (rest >> 3)) * 128;    // 64 row tiles
  const int colB = (rest & 7) * 128;
  const int wm = (wave >> 1) * 64, wn = (wave & 1) * 64;
  const int fr = lane & 15;
  const int q = lane >> 4, lx = lane & 7;
  const int offK0 = (q ^ lx) << 3, offK1 = ((q + 4) ^ lx) << 3;

  f32x4 acc[4][4];
  const f32x4 zero = {0.f, 0.f, 0.f, 0.f};
#pragma unroll
  for (int i = 0; i < 4; ++i)
#pragma unroll
    for (int j = 0; j < 4; ++j) acc[i][j] = zero;

  // staging pointers (advance 64 elems per staged tile)
  const bf16* aSrc[4]; const bf16* bSrc[4];
#pragma unroll
  for (int j = 0; j < 4; ++j) {
    const int c = t + 256 * j;
    const int row = c >> 3;
    const int qs = ((c & 7) ^ (row & 7)) << 3;
    aSrc[j] = Y + (size_t)(rowA + row) * 2048 + qs;
    bSrc[j] = ADJB + (size_t)(colB + row) * 1024 + qs;
  }

  auto stage = [&](int d) {
#pragma unroll
    for (int ja = 0; ja < 4; ++ja) {
      __builtin_amdgcn_global_load_lds((const uint32_t*)aSrc[ja],
                                       (uint32_t*)&sm.st.As[d][(t + 256 * ja) * 8], 16, 0, 0);
      aSrc[ja] += 64;
    }
#pragma unroll
    for (int jb = 0; jb < 4; ++jb) {
      __builtin_amdgcn_global_load_lds((const uint32_t*)bSrc[jb],
                                       (uint32_t*)&sm.st.Bs[d][(t + 256 * jb) * 8], 16, 0, 0);
      bSrc[jb] += 64;
    }
  };

  int rAb[4], rBb[4];
#pragma unroll
  for (int i = 0; i < 4; ++i) {
    rAb[i] = (wm + i * 16 + fr) * 64;
    rBb[i] = (wn + i * 16 + fr) * 64;
  }

  stage(0); stage(1);   // tiles 0,1: 16 loads in flight
  asm volatile("s_waitcnt vmcnt(8)" ::: "memory");   // tile 0 landed
  __builtin_amdgcn_s_barrier();                      // tile 0 visible to all
  __builtin_amdgcn_sched_barrier(0);

  bf16x8_t af0[4], bf0[4], af1[4], bf1[4];
  {
    const bf16* A_ = sm.st.As[0];
    const bf16* B_ = sm.st.Bs[0];
#pragma unroll
    for (int i = 0; i < 4; ++i) af0[i] = *reinterpret_cast<const bf16x8_t*>(&A_[rAb[i] + offK0]);
#pragma unroll
    for (int i = 0; i < 4; ++i) bf0[i] = *reinterpret_cast<const bf16x8_t*>(&B_[rBb[i] + offK0]);
  }

  int cur = 0;
  for (int kt = 0; kt < 32; ++kt) {
    const int nxt = cur ^ 1;
    const bf16* A_ = sm.st.As[cur];
    const bf16* B_ = sm.st.Bs[cur];
    // issue k1 reads (drain under MFMA k0)
#pragma unroll
    for (int i = 0; i < 4; ++i) af1[i] = *reinterpret_cast<const bf16x8_t*>(&A_[rAb[i] + offK1]);
#pragma unroll
    for (int i = 0; i < 4; ++i) bf1[i] = *reinterpret_cast<const bf16x8_t*>(&B_[rBb[i] + offK1]);
    asm volatile("s_waitcnt lgkmcnt(8)" ::: "memory");   // k0 frags ready
    __builtin_amdgcn_sched_barrier(0);
    __builtin_amdgcn_s_setprio(1);
#pragma unroll
    for (int i = 0; i < 4; ++i)
#pragma unroll
      for (int j = 0; j < 4; ++j)
        acc[i][j] = __builtin_amdgcn_mfma_f32_16x16x32_bf16(af0[i], bf0[j], acc[i][j], 0, 0, 0);
    __builtin_amdgcn_s_setprio(0);
    asm volatile("s_waitcnt lgkmcnt(0)" ::: "memory");   // k1 frags ready; buf[cur] fully read
    __builtin_amdgcn_sched_barrier(0);
    asm volatile("s_waitcnt vmcnt(0)" ::: "memory");     // tile kt+1 landed (issued 1 iter ago)
    __builtin_amdgcn_s_barrier();   // all waves done reading buf[cur]; tile kt+1 visible
    __builtin_amdgcn_sched_barrier(0);
    if (kt < 30) {
      stage(cur);                   // refill freed buffer with tile kt+2
      if (kt == 13) {               // next staged B-tile (16) crosses to s=1
        bSrc[0] += 1024 * 1024 - 1024;
        bSrc[1] += 1024 * 1024 - 1024;
        bSrc[2] += 1024 * 1024 - 1024;
        bSrc[3] += 1024 * 1024 - 1024;
      }
    }
    if (kt < 31) {                  // issue k0 reads of tile kt+1 (drain under MFMA k1)
      const bf16* An = sm.st.As[nxt];
      const bf16* Bn = sm.st.Bs[nxt];
#pragma unroll
      for (int i = 0; i < 4; ++i) af0[i] = *reinterpret_cast<const bf16x8_t*>(&An[rAb[i] + offK0]);
#pragma unroll
      for (int i = 0; i < 4; ++i) bf0[i] = *reinterpret_cast<const bf16x8_t*>(&Bn[rBb[i] + offK0]);
    }
    __builtin_amdgcn_s_setprio(1);
#pragma unroll
    for (int i = 0; i < 4; ++i)
#pragma unroll
      for (int j = 0; j < 4; ++j)
        acc[i][j] = __builtin_amdgcn_mfma_f32_16x16x32_bf16(af1[i], bf1[j], acc[i][j], 0, 0, 0);
    __builtin_amdgcn_s_setprio(0);
    cur = nxt;
  }

  // ---- epilogue weight preloads (union member 2 now owns LDS) ----
  for (int i = t; i < 512; i += 256) {       // W1s: 4096 elems as bf16x8
    const int r = i >> 3, c8 = i & 7;
    *reinterpret_cast<bf16x8_t*>(&sm.ep.W1s[r * 72 + c8 * 8]) =
        *reinterpret_cast<const bf16x8_t*>(&W1B[i * 8]);
  }
  for (int i = t; i < 640; i += 256) {       // A2s: 5120 elems as bf16x8
    const int r = i >> 3, c8 = i & 7;
    *reinterpret_cast<bf16x8_t*>(&sm.ep.A2s[r * 72 + c8 * 8]) =
        *reinterpret_cast<const bf16x8_t*>(&A2B[i * 8]);
  }
  if (t < 64) { sm.ep.HBs[t] = HBv[t]; sm.ep.Wrs[t] = W_read[t]; }
  const float pw = prelu_w[0];
  const float br = b_read[0];

  // ---- phase 2a: gc tile -> LDS bf16, layout [b2][w_local][c] pad 72 ----
  {
    const int b2w = wm >> 6;  // 0..1
#pragma unroll
    for (int i = 0; i < 4; ++i) {
      const int cc0 = i * 16 + q * 4;
#pragma unroll
      for (int j = 0; j < 4; ++j) {
        const int wl = wn + j * 16 + fr;
        bf16x4_t r;
        r.x = (bf16)acc[i][j][0]; r.y = (bf16)acc[i][j][1];
        r.z = (bf16)acc[i][j][2]; r.w = (bf16)acc[i][j][3];
        *reinterpret_cast<bf16x4_t*>(&sm.ep.gcs[b2w * 9216 + wl * 72 + cc0]) = r;
      }
    }
  }
  __syncthreads();

  const int b2 = wave >> 1, jh = wave & 1;
  const int b = (rowA >> 6) + b2;   // 2 batches per block

  f32x4 acc2[5][4];
#pragma unroll
  for (int i = 0; i < 5; ++i)
#pragma unroll
    for (int j = 0; j < 4; ++j) {
      if (i < 4) {
        f32x4 c0;
#pragma unroll
        for (int r = 0; r < 4; ++r) c0[r] = sm.ep.HBs[i * 16 + q * 4 + r];
        acc2[i][j] = c0;
      } else {
        acc2[i][j] = zero;
      }
    }

  // phase 2b: W1 @ gc
#pragma unroll
  for (int k2 = 0; k2 < 64; k2 += 32) {
    bf16x8_t af2[4], bf2[4];
#pragma unroll
    for (int i = 0; i < 4; ++i)
      af2[i] = *reinterpret_cast<const bf16x8_t*>(&sm.ep.W1s[(i * 16 + fr) * 72 + k2 + q * 8]);
#pragma unroll
    for (int j = 0; j < 4; ++j)
      bf2[j] = *reinterpret_cast<const bf16x8_t*>(&sm.ep.gcs[b2 * 9216 + (jh * 64 + j * 16 + fr) * 72 + k2 + q * 8]);
#pragma unroll
    for (int i = 0; i < 4; ++i)
#pragma unroll
      for (int j = 0; j < 4; ++j)
        acc2[i][j] = __builtin_amdgcn_mfma_f32_16x16x32_bf16(af2[i], bf2[j], acc2[i][j], 0, 0, 0);
  }

  // phase 3: [W2; W_read] @ h  — B-frags direct from swizzled HT global
#pragma unroll
  for (int k2 = 0; k2 < 64; k2 += 32) {
    const int off = k2 ? offK1 : offK0;  // (kq ^ (w&7))*8 with w&7 == lx
    bf16x8_t bh[4], af3[5];
#pragma unroll
    for (int j = 0; j < 4; ++j) {
      const int w = colB + jh * 64 + j * 16 + fr;
      bh[j] = *reinterpret_cast<const bf16x8_t*>(&HT[((size_t)(b << 10) + w) * 64 + off]);
    }
#pragma unroll
    for (int i = 0; i < 5; ++i)
      af3[i] = *reinterpret_cast<const bf16x8_t*>(&sm.ep.A2s[(i * 16 + fr) * 72 + k2 + q * 8]);
#pragma unroll
    for (int i = 0; i < 5; ++i)
#pragma unroll
      for (int j = 0; j < 4; ++j)
        acc2[i][j] = __builtin_amdgcn_mfma_f32_16x16x32_bf16(af3[i], bh[j], acc2[i][j], 0, 0, 0);
  }

  // epilogue: PReLU, write out2[b][0..63], reduce read output
  float rd[4] = {0.f, 0.f, 0.f, 0.f};
#pragma unroll
  for (int i = 0; i < 4; ++i) {
#pragma unroll
    for (int r = 0; r < 4; ++r) {
      const int o = i * 16 + q * 4 + r;
      const float wr = sm.ep.Wrs[o];
#pragma unroll
      for (int j = 0; j < 4; ++j) {
        const int wg = colB + jh * 64 + j * 16 + fr;
        float val = acc2[i][j][r];
        val = val >= 0.f ? val : pw * val;
        out2[(size_t)(b * 128 + o) * 1024 + wg] = val;
        rd[j] += wr * val;
      }
    }
  }
#pragma unroll
  for (int j = 0; j < 4; ++j) {
    rd[j] += __shfl_xor(rd[j], 16, 64);
    rd[j] += __shfl_xor(rd[j], 32, 64);
  }
  if (lane < 16) {
#pragma unroll
    for (int j = 0; j < 4; ++j) {
      const int wg = colB + jh * 64 + j * 16 + lane;
      out0[(size_t)b * 1024 + wg] = rd[j] + acc2[4][j][0] + br;
    }
  }
}

// ---------------------------------------------------------------------------
extern "C" void kernel_launch(void* const* d_in, const int* in_sizes, int n_in,
                              void* d_out, int out_size, void* d_ws, size_t ws_size,
                              hipStream_t stream) {
  (void)in_sizes; (void)n_in; (void)out_size; (void)ws_size;
  const float* x       = (const float*)d_in[0];
  const float* m       = (const float*)d_in[1];
  const float* u       = (const float*)d_in[2];
  const float* h       = (const float*)d_in[3];
  const float* adj     = (const float*)d_in[4];
  const float* W_in    = (const float*)d_in[5];
  const float* b_in    = (const float*)d_in[6];
  const float* W_gc    = (const float*)d_in[7];
  const float* b_gc    = (const float*)d_in[8];
  const float* W_out   = (const float*)d_in[9];
  const float* b_out   = (const float*)d_in[10];
  const float* W_read  = (const float*)d_in[11];
  const float* b_read  = (const float*)d_in[12];
  const float* prelu_w = (const float*)d_in[13];

  char* ws = (char*)d_ws;
  bf16*  Y    = (bf16*)(ws);                       // 33554432 B
  bf16*  ADJB = (bf16*)(ws + 33554432);            //  4194304 -> 37748736
  bf16*  HT   = (bf16*)(ws + 37748736);            // 16777216 -> 54525952
  bf16*  WAT  = (bf16*)(ws + 54525952);            //    16384 -> 54542336
  float* WYX  = (float*)(ws + 54542336);           //     2048 -> 54544384
  float* BIAS = (float*)(ws + 54544384);           //      512 -> 54544896
  bf16*  W1B  = (bf16*)(ws + 54544896);            //     8192 -> 54553088
  bf16*  A2B  = (bf16*)(ws + 54553088);            //    10240 -> 54563328
  float* HBv  = (float*)(ws + 54563328);           //      256 -> 54563584

  float* out0 = (float*)d_out;           // read  [B,1,N]  = 131072 f32
  float* out2 = out0 + 131072;           // out2  [B,128,N] f32

  hipLaunchKernelGGL(k_prep,  dim3(71),       dim3(256), 0, stream,
                     W_in, b_in, W_gc, b_gc, W_out, b_out, W_read,
                     WAT, WYX, BIAS, W1B, A2B, HBv);
  hipLaunchKernelGGL(k_build, dim3(10, 128),  dim3(256), 0, stream,
                     x, m, u, h, adj, WAT, WYX, BIAS, ADJB, Y, HT, out2);
  hipLaunchKernelGGL(k_gemm,  dim3(64, 8),    dim3(256), 0, stream,
                     Y, ADJB, HT, W1B, A2B, HBv, W_read, b_read, prelu_w, out0, out2);
}

// Round 10
// 174.783 us; speedup vs baseline: 1.0034x; 1.0034x over previous
//
#include <hip/hip_runtime.h>
#include <hip/hip_bf16.h>
#include <stdint.h>

// Problem constants (SpatialDecoder: B=128, N=1024, DM=64, S=2, D_IN=68)
#define NB 128
#define NN 1024
#define NDM 64

typedef __bf16 bf16;
typedef __bf16 bf16x8_t __attribute__((ext_vector_type(8)));
typedef __bf16 bf16x4_t __attribute__((ext_vector_type(4)));
typedef float f32x4 __attribute__((ext_vector_type(4)));

// ---------------------------------------------------------------------------
// k_prep: weight prep only (adj cast lives in k_build). Grid 71 x 256.
// ---------------------------------------------------------------------------
__global__ __launch_bounds__(256) void k_prep(
    const float* __restrict__ W_in, const float* __restrict__ b_in,
    const float* __restrict__ W_gc, const float* __restrict__ b_gc,
    const float* __restrict__ W_out, const float* __restrict__ b_out,
    const float* __restrict__ W_read,
    bf16* __restrict__ WAT, float* __restrict__ WYX,
    float* __restrict__ BIAS, bf16* __restrict__ W1B, bf16* __restrict__ A2B,
    float* __restrict__ HBv) {
  int i = blockIdx.x * 256 + threadIdx.x;
  if (i < 8192) {  // WAT
    int r = i >> 6, cc = i & 63;
    int cq = cc >> 3, j = cc & 7;
    int c = ((cq ^ (r & 7)) << 3) + j;
    int s = r >> 6, o = r & 63;
    float val = 0.f;
    for (int k = 0; k < 64; ++k) val += W_gc[o * 128 + s * 64 + k] * W_in[k * 68 + 4 + c];
    WAT[i] = (bf16)val;
  } else if (i < 8704) {  // WYX
    int idx = i - 8192;
    int r = idx >> 2, jj = idx & 3;
    int s = r >> 6, o = r & 63;
    float val = 0.f;
    for (int k = 0; k < 64; ++k) val += W_gc[o * 128 + s * 64 + k] * W_in[k * 68 + jj];
    WYX[idx] = val;
  } else if (i < 8832) {  // BIAS
    int r = i - 8704;
    int s = r >> 6, o = r & 63;
    float val = 0.f;
    for (int k = 0; k < 64; ++k) val += W_gc[o * 128 + s * 64 + k] * b_in[k];
    BIAS[r] = val;
  } else if (i < 12928) {  // W1B
    int j = i - 8832;
    int o = j >> 6, c = j & 63;
    W1B[j] = (bf16)W_out[o * 128 + c];
  } else if (i < 18048) {  // A2B (80x64)
    int j = i - 12928;
    int r = j >> 6, c = j & 63;
    float val = 0.f;
    if (r < 64) val = W_out[r * 128 + 64 + c];
    else if (r == 64) val = W_read[64 + c];
    A2B[j] = (bf16)val;
  } else if (i < 18112) {  // HBv
    int o = i - 18048;
    float val = b_out[o];
    for (int c = 0; c < 64; ++c) val += W_out[o * 128 + c] * b_gc[c];
    HBv[o] = val;
  }
}

// ---------------------------------------------------------------------------
// k_build (fused transpose + Y build). Grid (10, 128), 256 thr. (round-7)
// ---------------------------------------------------------------------------
__global__ __launch_bounds__(256) void k_build(
    const float* __restrict__ x, const float* __restrict__ m, const float* __restrict__ u,
    const float* __restrict__ h, const float* __restrict__ adj,
    const bf16* __restrict__ WAT,
    const float* __restrict__ WYX, const float* __restrict__ BIAS,
    bf16* __restrict__ adjb, bf16* __restrict__ Y, bf16* __restrict__ HT,
    float* __restrict__ out2) {
  __shared__ __align__(16) float T[64 * 128];     // 32 KB (reused as Y-tile)
  __shared__ __align__(16) bf16 HTs[128 * 64];    // 16 KB
  __shared__ __align__(16) bf16 WAs[128 * 64];    // 16 KB
  __shared__ __align__(16) float X4L[128 * 4];    // 2 KB
  __shared__ __align__(16) float WYXs[128 * 4];   // 2 KB
  __shared__ __align__(16) float biasL[128];
  const int t = threadIdx.x;

  if (blockIdx.x >= 8) {  // adj cast blocks: 256 blocks x 2048 float4
    const int chunk = (blockIdx.x - 8) * 128 + blockIdx.y;  // 0..255
#pragma unroll
    for (int k2 = 0; k2 < 8; ++k2) {
      int i = chunk * 2048 + k2 * 256 + t;
      float4 v = reinterpret_cast<const float4*>(adj)[i];
      bf16x4_t r;
      r.x = (bf16)v.x; r.y = (bf16)v.y; r.z = (bf16)v.z; r.w = (bf16)v.w;
      reinterpret_cast<bf16x4_t*>(adjb)[i] = r;
    }
    return;
  }

  const int vb = blockIdx.x * 128;
  const int b = blockIdx.y;

  for (int i = t; i < 2048; i += 256)
    __builtin_amdgcn_global_load_lds(
        (const uint32_t*)(h + (size_t)(b * 64 + (i >> 5)) * NN + vb + (i & 31) * 4),
        (uint32_t*)&T[i * 4], 16, 0, 0);
  for (int i = t; i < 1024; i += 256)
    __builtin_amdgcn_global_load_lds((const uint32_t*)(WAT + i * 8), (uint32_t*)&WAs[i * 8], 16, 0, 0);
  if (t < 128)
    __builtin_amdgcn_global_load_lds((const uint32_t*)(WYX + t * 4), (uint32_t*)&WYXs[t * 4], 16, 0, 0);
  if (t < 32)
    __builtin_amdgcn_global_load_lds((const uint32_t*)(BIAS + t * 4), (uint32_t*)&biasL[t * 4], 16, 0, 0);
  if (t < 128) {
    float4 x4;
    x4.x = x[(size_t)b * NN + vb + t];
    x4.y = m[(size_t)b * NN + vb + t];
    x4.z = u[(size_t)(b * 2) * NN + vb + t];
    x4.w = u[(size_t)(b * 2 + 1) * NN + vb + t];
    *reinterpret_cast<float4*>(&X4L[t * 4]) = x4;
  }
  __syncthreads();

  // transpose/pack: thread pair covers one v (HTs only)
  {
    const int v = t >> 1, half = t & 1;
#pragma unroll
    for (int cc = 0; cc < 4; ++cc) {
      int cq = half * 4 + cc;
      int cbase = (cq ^ (v & 7)) << 3;
      bf16x8_t pk;
#pragma unroll
      for (int j = 0; j < 8; ++j) pk[j] = (bf16)T[(cbase + j) * 128 + v];
      *reinterpret_cast<bf16x8_t*>(&HTs[v * 64 + cq * 8]) = pk;
    }
  }
  // h passthrough (exact f32) — last use of T as h-tile
  for (int i = t; i < 2048; i += 256) {
    int r = i >> 5, ck = i & 31;
    float4 hv = *reinterpret_cast<const float4*>(&T[r * 128 + ck * 4]);
    *reinterpret_cast<float4*>(&out2[(size_t)(b * 128 + 64 + r) * NN + vb + ck * 4]) = hv;
  }
  __syncthreads();

  // coalesced HT store: 16 KB contiguous per block
  {
    const bf16* HTs_b = HTs;
#pragma unroll
    for (int p = 0; p < 4; ++p) {
      int i = p * 256 + t;
      bf16x8_t v = *reinterpret_cast<const bf16x8_t*>(&HTs_b[i * 8]);
      *reinterpret_cast<bf16x8_t*>(&HT[((size_t)(b << 10) + vb) * 64 + i * 8]) = v;
    }
  }

  const int wave = t >> 6, lane = t & 63;
  const int q = lane >> 4, lx = lane & 7, o16 = lane & 15;
  const int offK0 = (q ^ lx) << 3, offK1 = ((q + 4) ^ lx) << 3;
  bf16* YT = reinterpret_cast<bf16*>(T);   // [128 rows][128 v] bf16 = 32 KB

#pragma unroll
  for (int vi = 0; vi < 2; ++vi) {
    const int vt = wave + vi * 4;
    const int vrow = vt * 16 + o16;
    bf16x8_t af0 = *reinterpret_cast<const bf16x8_t*>(&HTs[vrow * 64 + offK0]);
    bf16x8_t af1 = *reinterpret_cast<const bf16x8_t*>(&HTs[vrow * 64 + offK1]);
    float4 x4r[4];
#pragma unroll
    for (int r = 0; r < 4; ++r)
      x4r[r] = *reinterpret_cast<const float4*>(&X4L[(vt * 16 + q * 4 + r) * 4]);
    for (int nt = 0; nt < 8; ++nt) {
      const int rr = nt * 16 + o16;
      bf16x8_t bf0 = *reinterpret_cast<const bf16x8_t*>(&WAs[rr * 64 + offK0]);
      bf16x8_t bf1 = *reinterpret_cast<const bf16x8_t*>(&WAs[rr * 64 + offK1]);
      float bsv = biasL[rr];
      float4 wy = *reinterpret_cast<const float4*>(&WYXs[rr * 4]);
      f32x4 c0;
#pragma unroll
      for (int r = 0; r < 4; ++r)
        c0[r] = bsv + wy.x * x4r[r].x + wy.y * x4r[r].y + wy.z * x4r[r].z + wy.w * x4r[r].w;
      f32x4 acc = __builtin_amdgcn_mfma_f32_16x16x32_bf16(af0, bf0, c0, 0, 0, 0);
      acc = __builtin_amdgcn_mfma_f32_16x16x32_bf16(af1, bf1, acc, 0, 0, 0);
      bf16x4_t pk;
      pk.x = (bf16)acc[0]; pk.y = (bf16)acc[1]; pk.z = (bf16)acc[2]; pk.w = (bf16)acc[3];
      // LDS write, 8B chunk XOR-swizzled by row&7 (conflict-free)
      const int c8 = (vt * 4 + q) ^ ((rr & 7) << 2);
      *reinterpret_cast<bf16x4_t*>(&YT[rr * 128 + c8 * 4]) = pk;
    }
  }
  __syncthreads();

  // coalesced Y store: per instr 4 rows x 256B contiguous
#pragma unroll
  for (int p = 0; p < 8; ++p) {
    int i = p * 256 + t;
    int ro = i >> 4;                         // 0..127 = s*64+o
    int cc = (i & 15) * 2;                   // even logical 8B chunk
    int cs = cc ^ ((ro & 7) << 2);           // swizzled location
    bf16x8_t v = *reinterpret_cast<const bf16x8_t*>(&YT[ro * 128 + cs * 4]);
    int s = ro >> 6, o = ro & 63;
    *reinterpret_cast<bf16x8_t*>(&Y[(size_t)(b * 64 + o) * 2048 + s * 1024 + vb + (i & 15) * 8]) = v;
  }
}

// ---------------------------------------------------------------------------
// k_gemm: round-5 structure (proven best: 44.9-47.2 us). BM=256 x BN=128,
//   BK=64, 512 thr / 8 waves, grid (32,8) = 1 blk/CU; 3-deep A+B LDS ring,
//   one barrier/iter, cross-tile frag pipeline, counted vmcnt/lgkmcnt,
//   setprio, XCD swizzle. 2-blocks/CU anti-phase (round 9) FALSIFIED: the
//   LDS port is shared, and the split doubles per-CU staging+barrier costs.
// ---------------------------------------------------------------------------
__global__ __launch_bounds__(512, 2) void k_gemm(
    const bf16* __restrict__ Y, const bf16* __restrict__ ADJB,
    const bf16* __restrict__ HT,
    const bf16* __restrict__ W1B, const bf16* __restrict__ A2B,
    const float* __restrict__ HBv, const float* __restrict__ W_read,
    const float* __restrict__ b_read, const float* __restrict__ prelu_w,
    float* __restrict__ out0, float* __restrict__ out2) {
  __shared__ __align__(16) union SMem {
    struct { bf16 As[3][256 * 64]; bf16 Bs[3][128 * 64]; } st;  // 144 KB staging
    struct {
      bf16 gcs[4 * 128 * 72];   // 72 KB phase-2
      bf16 W1s[64 * 72];        // 9.2 KB
      bf16 A2s[80 * 72];        // 11.5 KB
      float HBs[64];
      float Wrs[64];
    } ep;
  } sm;

  const int t = threadIdx.x;
  const int wave = t >> 6, lane = t & 63;
  const int lin = blockIdx.y * 32 + blockIdx.x;
  const int xcd = lin & 7, rest = lin >> 3;
  const int rowA = (xcd * 4 + (rest >> 3)) * 256;
  const int colB = (rest & 7) * 128;
  const int wm = (wave >> 1) * 64, wn = (wave & 1) * 64;
  const int fr = lane & 15;
  const int q = lane >> 4, lx = lane & 7;
  const int offK0 = (q ^ lx) << 3, offK1 = ((q + 4) ^ lx) << 3;

  f32x4 acc[4][4];
  const f32x4 zero = {0.f, 0.f, 0.f, 0.f};
#pragma unroll
  for (int i = 0; i < 4; ++i)
#pragma unroll
    for (int j = 0; j < 4; ++j) acc[i][j] = zero;

  const bf16* aSrc[4]; const bf16* bSrc[2];
#pragma unroll
  for (int j = 0; j < 4; ++j) {
    const int c = t + 512 * j;
    const int row = c >> 3;
    const int qs = ((c & 7) ^ (row & 7)) << 3;
    aSrc[j] = Y + (size_t)(rowA + row) * 2048 + qs;
  }
#pragma unroll
  for (int j = 0; j < 2; ++j) {
    const int c = t + 512 * j;
    const int row = c >> 3;
    const int qs = ((c & 7) ^ (row & 7)) << 3;
    bSrc[j] = ADJB + (size_t)(colB + row) * 1024 + qs;
  }

  auto stage = [&](int d) {
#pragma unroll
    for (int ja = 0; ja < 4; ++ja) {
      __builtin_amdgcn_global_load_lds((const uint32_t*)aSrc[ja],
                                       (uint32_t*)&sm.st.As[d][(t + 512 * ja) * 8], 16, 0, 0);
      aSrc[ja] += 64;
    }
#pragma unroll
    for (int jb = 0; jb < 2; ++jb) {
      __builtin_amdgcn_global_load_lds((const uint32_t*)bSrc[jb],
                                       (uint32_t*)&sm.st.Bs[d][(t + 512 * jb) * 8], 16, 0, 0);
      bSrc[jb] += 64;
    }
  };

  int rAb[4], rBb[4];
#pragma unroll
  for (int i = 0; i < 4; ++i) {
    rAb[i] = (wm + i * 16 + fr) * 64;
    rBb[i] = (wn + i * 16 + fr) * 64;
  }

  stage(0); stage(1); stage(2);   // tiles 0,1,2: 18 loads in flight
  asm volatile("s_waitcnt vmcnt(12)" ::: "memory");  // tile 0 landed
  __builtin_amdgcn_s_barrier();                      // tile 0 visible to all
  __builtin_amdgcn_sched_barrier(0);

  bf16x8_t af0[4], bf0[4], af1[4], bf1[4];
  {
    const bf16* A_ = sm.st.As[0];
    const bf16* B_ = sm.st.Bs[0];
#pragma unroll
    for (int i = 0; i < 4; ++i) af0[i] = *reinterpret_cast<const bf16x8_t*>(&A_[rAb[i] + offK0]);
#pragma unroll
    for (int i = 0; i < 4; ++i) bf0[i] = *reinterpret_cast<const bf16x8_t*>(&B_[rBb[i] + offK0]);
  }

  int cur = 0;
  for (int kt = 0; kt < 32; ++kt) {
    const int nxt = (cur == 2) ? 0 : cur + 1;
    const bf16* A_ = sm.st.As[cur];
    const bf16* B_ = sm.st.Bs[cur];
    // issue k1 reads (drain under MFMA k0)
#pragma unroll
    for (int i = 0; i < 4; ++i) af1[i] = *reinterpret_cast<const bf16x8_t*>(&A_[rAb[i] + offK1]);
#pragma unroll
    for (int i = 0; i < 4; ++i) bf1[i] = *reinterpret_cast<const bf16x8_t*>(&B_[rBb[i] + offK1]);
    asm volatile("s_waitcnt lgkmcnt(8)" ::: "memory");   // k0 frags ready
    __builtin_amdgcn_sched_barrier(0);
    __builtin_amdgcn_s_setprio(1);
#pragma unroll
    for (int i = 0; i < 4; ++i)
#pragma unroll
      for (int j = 0; j < 4; ++j)
        acc[i][j] = __builtin_amdgcn_mfma_f32_16x16x32_bf16(af0[i], bf0[j], acc[i][j], 0, 0, 0);
    __builtin_amdgcn_s_setprio(0);
    asm volatile("s_waitcnt lgkmcnt(0)" ::: "memory");   // k1 frags ready; buf[cur] fully read
    __builtin_amdgcn_sched_barrier(0);
    if (kt < 30)       asm volatile("s_waitcnt vmcnt(6)" ::: "memory");  // tile kt+1 landed
    else if (kt == 30) asm volatile("s_waitcnt vmcnt(0)" ::: "memory");  // tile 31 landed
    __builtin_amdgcn_s_barrier();   // all waves done reading buf[cur]; tile kt+1 visible
    __builtin_amdgcn_sched_barrier(0);
    if (kt < 29) {
      stage(cur);                   // refill freed buffer with tile kt+3
      if (kt == 12) {               // next staged B-tile (16) crosses to s=1
        bSrc[0] += 1024 * 1024 - 1024;
        bSrc[1] += 1024 * 1024 - 1024;
      }
    }
    if (kt < 31) {                  // issue k0 reads of tile kt+1 (drain under MFMA k1)
      const bf16* An = sm.st.As[nxt];
      const bf16* Bn = sm.st.Bs[nxt];
#pragma unroll
      for (int i = 0; i < 4; ++i) af0[i] = *reinterpret_cast<const bf16x8_t*>(&An[rAb[i] + offK0]);
#pragma unroll
      for (int i = 0; i < 4; ++i) bf0[i] = *reinterpret_cast<const bf16x8_t*>(&Bn[rBb[i] + offK0]);
    }
    __builtin_amdgcn_s_setprio(1);
#pragma unroll
    for (int i = 0; i < 4; ++i)
#pragma unroll
      for (int j = 0; j < 4; ++j)
        acc[i][j] = __builtin_amdgcn_mfma_f32_16x16x32_bf16(af1[i], bf1[j], acc[i][j], 0, 0, 0);
    __builtin_amdgcn_s_setprio(0);
    cur = nxt;
  }

  // ---- epilogue weight preloads (union member 2 now owns LDS) ----
  {
    const int r = t >> 3, c8 = t & 7;  // 512 chunks == 512 threads
    *reinterpret_cast<bf16x8_t*>(&sm.ep.W1s[r * 72 + c8 * 8]) =
        *reinterpret_cast<const bf16x8_t*>(&W1B[t * 8]);
  }
  for (int i = t; i < 640; i += 512) {
    const int r = i >> 3, c8 = i & 7;
    *reinterpret_cast<bf16x8_t*>(&sm.ep.A2s[r * 72 + c8 * 8]) =
        *reinterpret_cast<const bf16x8_t*>(&A2B[i * 8]);
  }
  if (t < 64) { sm.ep.HBs[t] = HBv[t]; sm.ep.Wrs[t] = W_read[t]; }
  const float pw = prelu_w[0];
  const float br = b_read[0];

  // ---- phase 2a: gc tile -> LDS bf16, layout [b2][w_local][c] pad 72 ----
  {
    const int b2w = wm >> 6;  // 0..3
#pragma unroll
    for (int i = 0; i < 4; ++i) {
      const int cc0 = i * 16 + q * 4;
#pragma unroll
      for (int j = 0; j < 4; ++j) {
        const int wl = wn + j * 16 + fr;
        bf16x4_t r;
        r.x = (bf16)acc[i][j][0]; r.y = (bf16)acc[i][j][1];
        r.z = (bf16)acc[i][j][2]; r.w = (bf16)acc[i][j][3];
        *reinterpret_cast<bf16x4_t*>(&sm.ep.gcs[b2w * 9216 + wl * 72 + cc0]) = r;
      }
    }
  }
  __syncthreads();

  const int b2 = wave >> 1, jh = wave & 1;
  const int b = (rowA >> 6) + b2;   // 4 batches per block

  f32x4 acc2[5][4];
#pragma unroll
  for (int i = 0; i < 5; ++i)
#pragma unroll
    for (int j = 0; j < 4; ++j) {
      if (i < 4) {
        f32x4 c0;
#pragma unroll
        for (int r = 0; r < 4; ++r) c0[r] = sm.ep.HBs[i * 16 + q * 4 + r];
        acc2[i][j] = c0;
      } else {
        acc2[i][j] = zero;
      }
    }

  // phase 2b: W1 @ gc
#pragma unroll
  for (int k2 = 0; k2 < 64; k2 += 32) {
    bf16x8_t af2[4], bf2[4];
#pragma unroll
    for (int i = 0; i < 4; ++i)
      af2[i] = *reinterpret_cast<const bf16x8_t*>(&sm.ep.W1s[(i * 16 + fr) * 72 + k2 + q * 8]);
#pragma unroll
    for (int j = 0; j < 4; ++j)
      bf2[j] = *reinterpret_cast<const bf16x8_t*>(&sm.ep.gcs[b2 * 9216 + (jh * 64 + j * 16 + fr) * 72 + k2 + q * 8]);
#pragma unroll
    for (int i = 0; i < 4; ++i)
#pragma unroll
      for (int j = 0; j < 4; ++j)
        acc2[i][j] = __builtin_amdgcn_mfma_f32_16x16x32_bf16(af2[i], bf2[j], acc2[i][j], 0, 0, 0);
  }

  // phase 3: [W2; W_read] @ h  — B-frags direct from swizzled HT global
#pragma unroll
  for (int k2 = 0; k2 < 64; k2 += 32) {
    const int off = k2 ? offK1 : offK0;  // (kq ^ (w&7))*8 with w&7 == lx
    bf16x8_t bh[4], af3[5];
#pragma unroll
    for (int j = 0; j < 4; ++j) {
      const int w = colB + jh * 64 + j * 16 + fr;
      bh[j] = *reinterpret_cast<const bf16x8_t*>(&HT[((size_t)(b << 10) + w) * 64 + off]);
    }
#pragma unroll
    for (int i = 0; i < 5; ++i)
      af3[i] = *reinterpret_cast<const bf16x8_t*>(&sm.ep.A2s[(i * 16 + fr) * 72 + k2 + q * 8]);
#pragma unroll
    for (int i = 0; i < 5; ++i)
#pragma unroll
      for (int j = 0; j < 4; ++j)
        acc2[i][j] = __builtin_amdgcn_mfma_f32_16x16x32_bf16(af3[i], bh[j], acc2[i][j], 0, 0, 0);
  }

  // epilogue: PReLU, write out2[b][0..63], reduce read output
  float rd[4] = {0.f, 0.f, 0.f, 0.f};
#pragma unroll
  for (int i = 0; i < 4; ++i) {
#pragma unroll
    for (int r = 0; r < 4; ++r) {
      const int o = i * 16 + q * 4 + r;
      const float wr = sm.ep.Wrs[o];
#pragma unroll
      for (int j = 0; j < 4; ++j) {
        const int wg = colB + jh * 64 + j * 16 + fr;
        float val = acc2[i][j][r];
        val = val >= 0.f ? val : pw * val;
        out2[(size_t)(b * 128 + o) * 1024 + wg] = val;
        rd[j] += wr * val;
      }
    }
  }
#pragma unroll
  for (int j = 0; j < 4; ++j) {
    rd[j] += __shfl_xor(rd[j], 16, 64);
    rd[j] += __shfl_xor(rd[j], 32, 64);
  }
  if (lane < 16) {
#pragma unroll
    for (int j = 0; j < 4; ++j) {
      const int wg = colB + jh * 64 + j * 16 + lane;
      out0[(size_t)b * 1024 + wg] = rd[j] + acc2[4][j][0] + br;
    }
  }
}

// ---------------------------------------------------------------------------
extern "C" void kernel_launch(void* const* d_in, const int* in_sizes, int n_in,
                              void* d_out, int out_size, void* d_ws, size_t ws_size,
                              hipStream_t stream) {
  (void)in_sizes; (void)n_in; (void)out_size; (void)ws_size;
  const float* x       = (const float*)d_in[0];
  const float* m       = (const float*)d_in[1];
  const float* u       = (const float*)d_in[2];
  const float* h       = (const float*)d_in[3];
  const float* adj     = (const float*)d_in[4];
  const float* W_in    = (const float*)d_in[5];
  const float* b_in    = (const float*)d_in[6];
  const float* W_gc    = (const float*)d_in[7];
  const float* b_gc    = (const float*)d_in[8];
  const float* W_out   = (const float*)d_in[9];
  const float* b_out   = (const float*)d_in[10];
  const float* W_read  = (const float*)d_in[11];
  const float* b_read  = (const float*)d_in[12];
  const float* prelu_w = (const float*)d_in[13];

  char* ws = (char*)d_ws;
  bf16*  Y    = (bf16*)(ws);                       // 33554432 B
  bf16*  ADJB = (bf16*)(ws + 33554432);            //  4194304 -> 37748736
  bf16*  HT   = (bf16*)(ws + 37748736);            // 16777216 -> 54525952
  bf16*  WAT  = (bf16*)(ws + 54525952);            //    16384 -> 54542336
  float* WYX  = (float*)(ws + 54542336);           //     2048 -> 54544384
  float* BIAS = (float*)(ws + 54544384);           //      512 -> 54544896
  bf16*  W1B  = (bf16*)(ws + 54544896);            //     8192 -> 54553088
  bf16*  A2B  = (bf16*)(ws + 54553088);            //    10240 -> 54563328
  float* HBv  = (float*)(ws + 54563328);           //      256 -> 54563584

  float* out0 = (float*)d_out;           // read  [B,1,N]  = 131072 f32
  float* out2 = out0 + 131072;           // out2  [B,128,N] f32

  hipLaunchKernelGGL(k_prep,  dim3(71),       dim3(256), 0, stream,
                     W_in, b_in, W_gc, b_gc, W_out, b_out, W_read,
                     WAT, WYX, BIAS, W1B, A2B, HBv);
  hipLaunchKernelGGL(k_build, dim3(10, 128),  dim3(256), 0, stream,
                     x, m, u, h, adj, WAT, WYX, BIAS, ADJB, Y, HT, out2);
  hipLaunchKernelGGL(k_gemm,  dim3(32, 8),    dim3(512), 0, stream,
                     Y, ADJB, HT, W1B, A2B, HBv, W_read, b_read, prelu_w, out0, out2);
}